// Round 10
// baseline (348.231 us; speedup 1.0000x reference)
//
#include <hip/hip_runtime.h>
#include <stdint.h>

#define B_SZ    2
#define L_SEQ   2048
#define DMODEL  768
#define DSTATE  16
#define DINNER  1536
#define DTRANK  48
#define M_ROWS  4096      // B*L
#define NSEG    8
#define SEGL    256
#define NSC     8         // superchunks per segment
#define SCL     32        // steps per superchunk
#define KSPLIT  8         // gemm2 split-K slabs

typedef __attribute__((ext_vector_type(8))) short bf16x8;
typedef __attribute__((ext_vector_type(4))) float f32x4;
typedef __attribute__((ext_vector_type(2))) float f32x2;
typedef __attribute__((ext_vector_type(4))) unsigned int u32x4;
typedef __attribute__((ext_vector_type(2))) unsigned int u32x2;

__device__ __forceinline__ unsigned short f2bf(float f) {
  unsigned int u = __float_as_uint(f);
  u += 0x7FFFu + ((u >> 16) & 1u);          // RNE
  return (unsigned short)(u >> 16);
}
__device__ __forceinline__ unsigned int pack2bf(float a, float b) {
  return (unsigned int)f2bf(a) | ((unsigned int)f2bf(b) << 16);
}
__device__ __forceinline__ float fexp(float x) {
  return __builtin_amdgcn_exp2f(x * 1.44269504088896340736f);
}
__device__ __forceinline__ float sigm(float x) {
  return 1.0f / (1.0f + fexp(-x));
}
// softplus(v) = max(v,0) + ln2*log2(1+exp2(-|v|*log2e)) — 3 HW transcendentals, no libm
__device__ __forceinline__ float softplus(float v) {
  float e = __builtin_amdgcn_exp2f(-fabsf(v) * 1.44269504f);
  return fmaxf(v, 0.f) + 0.69314718056f * __builtin_amdgcn_logf(1.f + e);
}

template <int CTRL>
__device__ __forceinline__ float dpp_add(float v) {
  int x = __builtin_amdgcn_update_dpp(0, __float_as_int(v), CTRL, 0xF, 0xF, true);
  return v + __int_as_float(x);
}
__device__ __forceinline__ float quad_sum(float v) {
  v = dpp_add<0xB1>(v);   // quad_perm [1,0,3,2]
  v = dpp_add<0x4E>(v);   // quad_perm [2,3,0,1]
  return v;
}
__device__ __forceinline__ float row16_sum(float v) {
  v = dpp_add<0xB1>(v);
  v = dpp_add<0x4E>(v);
  v = dpp_add<0x124>(v);  // row_ror:4
  v = dpp_add<0x128>(v);  // row_ror:8
  return v;
}

// async global->LDS, 16B per lane; LDS dest is wave-uniform base + lane*16
__device__ __forceinline__ void gload_lds(const unsigned short* g, unsigned short* l) {
  __builtin_amdgcn_global_load_lds((__attribute__((address_space(1))) void*)g,
                                   (__attribute__((address_space(3))) void*)l, 16, 0, 0);
}

// ---------------------------------------------------------------- casts ----
__global__ void cast_all_kernel(const float* __restrict__ x, const float* __restrict__ w1,
                                const float* __restrict__ w2, const float* __restrict__ w3,
                                const float* __restrict__ dtw,
                                unsigned short* __restrict__ xbf, unsigned short* __restrict__ w1bf,
                                unsigned short* __restrict__ w2bf, unsigned short* __restrict__ w3bf,
                                unsigned short* __restrict__ dtwbf) {
  int i = blockIdx.x * 256 + threadIdx.x;
  const int n_x = M_ROWS * DMODEL;
  const int n_w1 = 2 * DINNER * DMODEL;
  const int n_w3 = DMODEL * DINNER;
  const int n_w2 = 128 * DINNER;
  const int n_dtw = DINNER * 64;
  if (i < n_x)  { xbf[i] = f2bf(x[i]); return; }  i -= n_x;
  if (i < n_w1) { w1bf[i] = f2bf(w1[i]); return; } i -= n_w1;
  if (i < n_w3) { w3bf[i] = f2bf(w3[i]); return; } i -= n_w3;
  if (i < n_w2) {
    int row = i / DINNER, col = i - row * DINNER;
    w2bf[i] = (row < (DTRANK + 2 * DSTATE)) ? f2bf(w2[row * DINNER + col]) : (unsigned short)0;
    return;
  }
  i -= n_w2;
  if (i < n_dtw) {
    int row = i >> 6, col = i & 63;
    dtwbf[i] = (col < DTRANK) ? f2bf(dtw[row * DTRANK + col]) : (unsigned short)0;
  }
}

// merged: reduce 8 gemm2 slabs + cast dt_low (padded K=64) + B/C transpose
__global__ void xdbl_pack_kernel(const float* __restrict__ xdblS,
                                 unsigned short* __restrict__ dtlbf,
                                 float* __restrict__ BCt) {
  const int SLAB = M_ROWS * 128;
  int i = blockIdx.x * 256 + threadIdx.x;
  const int n_dtl = M_ROWS * 64;            // 262144
  if (i < n_dtl) {
    int row = i >> 6, col = i & 63;
    if (col < DTRANK) {
      float v = 0.f;
#pragma unroll
      for (int z = 0; z < KSPLIT; z++) v += xdblS[(size_t)z * SLAB + row * 128 + col];
      dtlbf[i] = f2bf(v);
    } else dtlbf[i] = 0;
    return;
  }
  i -= n_dtl;                               // 32768 entries
  int l4 = i & 511;
  int j  = (i >> 9) & 31;
  int b  = (i >> 14) & 1;
  f32x4 o;
#pragma unroll
  for (int k = 0; k < 4; k++) {
    float v = 0.f;
    size_t base = ((size_t)b * L_SEQ + l4 * 4 + k) * 128 + DTRANK + j;
#pragma unroll
    for (int z = 0; z < KSPLIT; z++) v += xdblS[(size_t)z * SLAB + base];
    o[k] = v;
  }
  *(f32x4*)(BCt + ((size_t)b * 32 + j) * L_SEQ + l4 * 4) = o;
}

// ------------------------------- async bf16 MFMA GEMM (B^T), m97 structure ----
__global__ __launch_bounds__(256, 2) void gemm_async(
    const unsigned short* __restrict__ A, const unsigned short* __restrict__ Bt,
    float* __restrict__ C, int K, int KS, int ldc, long slab) {
  __shared__ unsigned short As[128 * 32];
  __shared__ unsigned short Bs[128 * 32];
  const int tid = threadIdx.x;
  const int lane = tid & 63;
  const int wv = tid >> 6;
  const int m0 = blockIdx.x * 128;
  const int n0 = blockIdx.y * 128;
  const int ks = blockIdx.z * KS, ke = ks + KS;
  float* Cz = C + (size_t)blockIdx.z * slab;
  const int wr = (wv >> 1) * 64, wc = (wv & 1) * 64;
  const int lm = lane & 15, q = lane >> 4;
  const int srow = wv * 16 + (lane >> 2);   // staging row within 64-row half
  const int scol = (lane & 3) * 8;          // staging col (elems)

  f32x4 acc[4][4] = {};

  for (int k0 = ks; k0 < ke; k0 += 32) {
#pragma unroll
    for (int j = 0; j < 2; j++) {
      gload_lds(A + (size_t)(m0 + j * 64 + srow) * K + k0 + scol, &As[(j * 64 + wv * 16) * 32]);
      gload_lds(Bt + (size_t)(n0 + j * 64 + srow) * K + k0 + scol, &Bs[(j * 64 + wv * 16) * 32]);
    }
    __syncthreads();
    bf16x8 af[4], bq[4];
#pragma unroll
    for (int mt = 0; mt < 4; mt++)
      af[mt] = *(const bf16x8*)&As[(wr + mt * 16 + lm) * 32 + q * 8];
#pragma unroll
    for (int nt = 0; nt < 4; nt++)
      bq[nt] = *(const bf16x8*)&Bs[(wc + nt * 16 + lm) * 32 + q * 8];
#pragma unroll
    for (int mt = 0; mt < 4; mt++)
#pragma unroll
      for (int nt = 0; nt < 4; nt++)
        acc[mt][nt] = __builtin_amdgcn_mfma_f32_16x16x32_bf16(af[mt], bq[nt], acc[mt][nt], 0, 0, 0);
    __syncthreads();
  }

#pragma unroll
  for (int mt = 0; mt < 4; mt++) {
    int row0 = m0 + wr + mt * 16 + q * 4;
#pragma unroll
    for (int nt = 0; nt < 4; nt++) {
      int col = n0 + wc + nt * 16 + lm;
#pragma unroll
      for (int i = 0; i < 4; i++)
        Cz[(size_t)(row0 + i) * ldc + col] = acc[mt][nt][i];
    }
  }
}

// --------------------- padded VGPR-staging GEMM for the dt projection ----
__global__ __launch_bounds__(256, 2) void gemm_dt(
    const unsigned short* __restrict__ A, const unsigned short* __restrict__ Bt,
    float* __restrict__ C, int K, int ldc, const float* __restrict__ bias) {
  __shared__ unsigned short As[128 * 40];
  __shared__ unsigned short Bs[128 * 40];
  const int tid = threadIdx.x;
  const int m0 = blockIdx.x * 128;
  const int n0 = blockIdx.y * 128;
  const int lane = tid & 63;
  const int wave = tid >> 6;
  const int wr = (wave >> 1) * 64, wc = (wave & 1) * 64;
  const int lm = lane & 15, q = lane >> 4;
  const int r = tid >> 2, sg = (tid & 3) * 8;

  f32x4 acc[4][4] = {};

  for (int k0 = 0; k0 < K; k0 += 32) {
    u32x4 a0 = *(const u32x4*)(A + (size_t)(m0 + r) * K + k0 + sg);
    u32x4 a1 = *(const u32x4*)(A + (size_t)(m0 + r + 64) * K + k0 + sg);
    u32x4 b0 = *(const u32x4*)(Bt + (size_t)(n0 + r) * K + k0 + sg);
    u32x4 b1 = *(const u32x4*)(Bt + (size_t)(n0 + r + 64) * K + k0 + sg);
    __syncthreads();
    *(u32x4*)&As[r * 40 + sg] = a0;
    *(u32x4*)&As[(r + 64) * 40 + sg] = a1;
    *(u32x4*)&Bs[r * 40 + sg] = b0;
    *(u32x4*)&Bs[(r + 64) * 40 + sg] = b1;
    __syncthreads();
    bf16x8 af[4], bq[4];
#pragma unroll
    for (int mt = 0; mt < 4; mt++)
      af[mt] = *(const bf16x8*)&As[(wr + mt * 16 + lm) * 40 + q * 8];
#pragma unroll
    for (int nt = 0; nt < 4; nt++)
      bq[nt] = *(const bf16x8*)&Bs[(wc + nt * 16 + lm) * 40 + q * 8];
#pragma unroll
    for (int mt = 0; mt < 4; mt++)
#pragma unroll
      for (int nt = 0; nt < 4; nt++)
        acc[mt][nt] = __builtin_amdgcn_mfma_f32_16x16x32_bf16(af[mt], bq[nt], acc[mt][nt], 0, 0, 0);
  }

#pragma unroll
  for (int mt = 0; mt < 4; mt++) {
    int row0 = m0 + wr + mt * 16 + q * 4;
    float bs4[4];
#pragma unroll
    for (int i = 0; i < 4; i++) bs4[i] = bias[row0 + i];
#pragma unroll
    for (int nt = 0; nt < 4; nt++) {
      int col = n0 + wc + nt * 16 + lm;
#pragma unroll
      for (int i = 0; i < 4; i++)
        C[(size_t)(row0 + i) * ldc + col] = softplus(acc[mt][nt][i] + bs4[i]);
    }
  }
}

// ---- fused depthwise conv+SiLU -> xcbf + xcT, then z-half SiLU -> szT ------
__global__ __launch_bounds__(256) void conv_silu_zt(const float* __restrict__ xz,
                                                    const float* __restrict__ cw,
                                                    const float* __restrict__ cb,
                                                    unsigned short* __restrict__ xcbf,
                                                    unsigned short* __restrict__ xcT,
                                                    unsigned short* __restrict__ szT) {
  __shared__ float tl[67 * 68];
  __shared__ unsigned short xs[64 * 80];
  __shared__ float cws[256];
  __shared__ float cbs[64];
  const int r0 = blockIdx.x * 64;     // global row b*L+l
  const int c0 = blockIdx.y * 64;     // channel d
  const int t = threadIdx.x;
  cws[t] = cw[(c0 + (t >> 2)) * 4 + (t & 3)];
  if (t < 64) cbs[t] = cb[c0 + t];
  const bool lowedge = (r0 & (L_SEQ - 1)) == 0;
#pragma unroll
  for (int it = 0; it < 5; it++) {
    int idx = t + it * 256;
    int rr = idx >> 4;
    int cs4 = (idx & 15) * 4;
    if (rr < 67) {
      f32x4 v;
      if (lowedge && rr < 3) v = (f32x4){0.f, 0.f, 0.f, 0.f};
      else v = *(const f32x4*)(xz + (size_t)(r0 + rr - 3) * 3072 + c0 + cs4);
      *(f32x4*)&tl[rr * 68 + cs4] = v;
    }
  }
  __syncthreads();
  {
    const int cs = (t & 15) * 4;
    f32x4 w0, w1, w2, w3, cbv;
#pragma unroll
    for (int j = 0; j < 4; j++) {
      w0[j] = cws[(cs + j) * 4 + 0];
      w1[j] = cws[(cs + j) * 4 + 1];
      w2[j] = cws[(cs + j) * 4 + 2];
      w3[j] = cws[(cs + j) * 4 + 3];
      cbv[j] = cbs[cs + j];
    }
#pragma unroll
    for (int it = 0; it < 4; it++) {
      int r = (t >> 4) + it * 16;
      f32x4 t0 = *(const f32x4*)&tl[(r + 0) * 68 + cs];
      f32x4 t1 = *(const f32x4*)&tl[(r + 1) * 68 + cs];
      f32x4 t2 = *(const f32x4*)&tl[(r + 2) * 68 + cs];
      f32x4 t3 = *(const f32x4*)&tl[(r + 3) * 68 + cs];
      f32x4 acc = cbv + w0 * t0 + w1 * t1 + w2 * t2 + w3 * t3;
#pragma unroll
      for (int j = 0; j < 4; j++) acc[j] = acc[j] * sigm(acc[j]);
      u32x2 pk;
      pk[0] = pack2bf(acc[0], acc[1]);
      pk[1] = pack2bf(acc[2], acc[3]);
      *(u32x2*)(xcbf + (size_t)(r0 + r) * DINNER + c0 + cs) = pk;
      *(u32x2*)&xs[r * 80 + cs] = pk;
    }
  }
  __syncthreads();
#pragma unroll
  for (int it = 0; it < 4; it++) {
    int idx = t + it * 256;
    int rr = idx >> 4, cs = idx & 15;
    f32x4 v = *(const f32x4*)(xz + (size_t)(r0 + rr) * 3072 + DINNER + c0 + cs * 4);
#pragma unroll
    for (int p = 0; p < 4; p++) v[p] = v[p] * sigm(v[p]);
    *(f32x4*)&tl[rr * 68 + cs * 4] = v;
  }
#pragma unroll
  for (int it = 0; it < 2; it++) {
    int idx = t + it * 256;
    int cc = idx & 63, rs = idx >> 6;
    unsigned int w[4];
#pragma unroll
    for (int p = 0; p < 4; p++) {
      unsigned int lo = xs[(rs * 8 + 2 * p) * 80 + cc];
      unsigned int hi = xs[(rs * 8 + 2 * p + 1) * 80 + cc];
      w[p] = lo | (hi << 16);
    }
    *(u32x4*)(xcT + (size_t)(c0 + cc) * M_ROWS + r0 + rs * 8) = *(u32x4*)w;
  }
  __syncthreads();
#pragma unroll
  for (int it = 0; it < 2; it++) {
    int idx = t + it * 256;
    int cc = idx & 63, rs = idx >> 6;
    unsigned int w[4];
#pragma unroll
    for (int p = 0; p < 4; p++)
      w[p] = pack2bf(tl[(rs * 8 + 2 * p) * 68 + cc], tl[(rs * 8 + 2 * p + 1) * 68 + cc]);
    *(u32x4*)(szT + (size_t)(c0 + cc) * M_ROWS + r0 + rs * 8) = *(u32x4*)w;
  }
}

// ------------------------------------------------ segmented selective scan ----
// 256-thr block = 4 waves, each wave an independent (4-channel group, batch,
// segment) scanner. dt/xc/sz staged via a small wave-private LDS quarter;
// B/C rows read DIRECTLY from global (BCt = 1 MB, L2-resident; 4-way
// dl-redundancy is free). No barriers. LDS: FULL=1 ~16 KB, FULL=0 ~4.6 KB.
template <int FULL>
__global__ __launch_bounds__(256) void scan_seg(
    const float* __restrict__ dtT, const unsigned short* __restrict__ xcT,
    const float* __restrict__ BCt, const unsigned short* __restrict__ szT,
    const float* __restrict__ A_log, const float* __restrict__ Dp,
    const float* __restrict__ HIN, float* __restrict__ P, float* __restrict__ HL,
    unsigned short* __restrict__ ybf) {
  __shared__ float dtS[4][4 * 36];
  __shared__ float dtxS[4][4 * 36];
  __shared__ unsigned int xcR[FULL ? 4 : 1][FULL ? 4 * 18 : 1];
  __shared__ unsigned int szR[FULL ? 4 : 1][FULL ? 4 * 18 : 1];
  __shared__ float ysh[FULL ? 4 : 1][FULL ? 16 * 36 : 1];
  const int tid = threadIdx.x;
  const int wv = tid >> 6;
  const int lane = tid & 63;
  const int s = lane & 15, dl = lane >> 4;
  const int d0 = blockIdx.x * 16 + wv * 4;
  const int d = d0 + dl;
  const int b = blockIdx.y;
  const int seg = blockIdx.z;
  const int lseg = seg * SEGL;
  const size_t rbase = (size_t)b * L_SEQ + lseg;
  const float a2 = -fexp(A_log[d * 16 + s]) * 1.44269504f;
  const float dpv = Dp[d];
  const float* dtbase = dtT + (size_t)d0 * M_ROWS + rbase;
  const unsigned short* xcbase = xcT + (size_t)d0 * M_ROWS + rbase;
  const unsigned short* szbase = szT + (size_t)d0 * M_ROWS + rbase;
  const float* Brow = BCt + ((size_t)b * 32 + s) * L_SEQ + lseg;
  const float* Crow = Brow + 16 * L_SEQ;
  const int ch = lane >> 4, li = lane & 15;     // staging map
  float* dtSw = dtS[wv];
  float* dtxSw = dtxS[wv];
  float* ywp = FULL ? &ysh[wv][(dl * 4 + (s >> 2)) * 36 + (s & 3)] : nullptr;
  const bool sb0 = (s & 1) != 0, sb1 = (s & 2) != 0;
  float h = 0.f, sdt = 0.f;
  size_t o = (((size_t)seg * B_SZ + b) * DINNER + d) * 16 + s;
  if (FULL) h = HIN[o];

#pragma unroll 1
  for (int c = 0; c < NSC; c++) {
    const int l0 = c * SCL;
    {
      f32x2 dt = *(const f32x2*)(dtbase + (size_t)ch * M_ROWS + l0 + li * 2);
      unsigned int xc = *(const unsigned int*)(xcbase + (size_t)ch * M_ROWS + l0 + li * 2);
      if (!FULL) sdt += dt[0] + dt[1];
      f32x2 xf;
      xf[0] = __uint_as_float(xc << 16);
      xf[1] = __uint_as_float(xc & 0xFFFF0000u);
      *(f32x2*)&dtSw[ch * 36 + li * 2] = dt;
      f32x2 dtx = dt * xf;
      *(f32x2*)&dtxSw[ch * 36 + li * 2] = dtx;
      if (FULL) {
        xcR[wv][ch * 18 + li] = xc;
        szR[wv][ch * 18 + li] = *(const unsigned int*)(szbase + (size_t)ch * M_ROWS + l0 + li * 2);
      }
    }
#pragma unroll
    for (int g = 0; g < 4; g++) {
      const int l0g = g * 8;
      f32x4 dta = *(const f32x4*)&dtSw[dl * 36 + l0g];
      f32x4 dtb = *(const f32x4*)&dtSw[dl * 36 + l0g + 4];
      f32x4 xa  = *(const f32x4*)&dtxSw[dl * 36 + l0g];
      f32x4 xb  = *(const f32x4*)&dtxSw[dl * 36 + l0g + 4];
      f32x4 Ba  = *(const f32x4*)(Brow + l0 + l0g);
      f32x4 Bb  = *(const f32x4*)(Brow + l0 + l0g + 4);
      f32x4 Ca, Cb;
      if (FULL) {
        Ca = *(const f32x4*)(Crow + l0 + l0g);
        Cb = *(const f32x4*)(Crow + l0 + l0g + 4);
      }
      float p8[8];
#pragma unroll
      for (int j = 0; j < 8; j++) {
        float dtj = (j < 4) ? dta[j] : dtb[j - 4];
        float dxj = (j < 4) ? xa[j]  : xb[j - 4];
        float Bj  = (j < 4) ? Ba[j]  : Bb[j - 4];
        float a = __builtin_amdgcn_exp2f(dtj * a2);
        h = a * h + dxj * Bj;
        if (FULL) {
          float Cj = (j < 4) ? Ca[j] : Cb[j - 4];
          p8[j] = h * Cj;
        }
      }
      if (FULL) {
#pragma unroll
        for (int half = 0; half < 2; half++) {
          float q0 = quad_sum(p8[half * 4 + 0]);
          float q1 = quad_sum(p8[half * 4 + 1]);
          float q2 = quad_sum(p8[half * 4 + 2]);
          float q3 = quad_sum(p8[half * 4 + 3]);
          float v01 = sb0 ? q1 : q0;
          float v23 = sb0 ? q3 : q2;
          ywp[g * 8 + half * 4] = sb1 ? v23 : v01;
        }
      }
    }
    if (FULL) {
      f32x2 y0 = *(const f32x2*)&ysh[wv][(dl * 4 + 0) * 36 + s * 2];
      f32x2 y1 = *(const f32x2*)&ysh[wv][(dl * 4 + 1) * 36 + s * 2];
      f32x2 y2 = *(const f32x2*)&ysh[wv][(dl * 4 + 2) * 36 + s * 2];
      f32x2 y3 = *(const f32x2*)&ysh[wv][(dl * 4 + 3) * 36 + s * 2];
      f32x2 ys = y0 + y1 + y2 + y3;
      unsigned int xcu = xcR[wv][dl * 18 + s];
      unsigned int szu = szR[wv][dl * 18 + s];
      float xcf[2] = {__uint_as_float(xcu << 16), __uint_as_float(xcu & 0xFFFF0000u)};
      float szf[2] = {__uint_as_float(szu << 16), __uint_as_float(szu & 0xFFFF0000u)};
      size_t rr0 = rbase + c * SCL + s * 2;
#pragma unroll
      for (int i = 0; i < 2; i++) {
        float yv = ys[i] + xcf[i] * dpv;
        ybf[(rr0 + i) * DINNER + d] = f2bf(yv * szf[i]);
      }
    }
  }
  if (!FULL) {
    sdt = row16_sum(sdt);
    P[o] = __builtin_amdgcn_exp2f(a2 * sdt);
    HL[o] = h;
  }
}

__global__ void scan_comb(const float* __restrict__ P, const float* __restrict__ HL,
                          float* __restrict__ HIN) {
  int tg = blockIdx.x * 256 + threadIdx.x;  // 49152
  int s = tg & 15;
  int rem = tg >> 4;
  int d = rem % DINNER;
  int b = rem / DINNER;
  float h = 0.f;
  for (int g = 0; g < NSEG; g++) {
    size_t o = (((size_t)g * B_SZ + b) * DINNER + d) * 16 + s;
    HIN[o] = h;
    if (g < NSEG - 1) h = P[o] * h + HL[o];
  }
}

// -------------------------------------------------------------- launcher ----
extern "C" void kernel_launch(void* const* d_in, const int* in_sizes, int n_in,
                              void* d_out, int out_size, void* d_ws, size_t ws_size,
                              hipStream_t stream) {
  const float* x    = (const float*)d_in[0];
  const float* w1   = (const float*)d_in[1];
  const float* cw   = (const float*)d_in[2];
  const float* cb   = (const float*)d_in[3];
  const float* alog = (const float*)d_in[4];
  const float* Dp   = (const float*)d_in[5];
  const float* w2   = (const float*)d_in[6];
  const float* dtw  = (const float*)d_in[7];
  const float* dtb  = (const float*)d_in[8];
  const float* w3   = (const float*)d_in[9];
  float* out = (float*)d_out;
  char* ws = (char*)d_ws;

  size_t off = 0;
  auto alloc = [&](size_t bytes) { size_t o = off; off += (bytes + 255) & ~(size_t)255; return o; };
  // xz region reused: after conv+szT consume it, dtT and ybf overlay it.
  char*           xzr   = ws + alloc((size_t)M_ROWS * 3072 * 4);
  float*          xz    = (float*)xzr;
  float*          dtT   = (float*)xzr;                                          // [1536][4096] f32
  unsigned short* ybf   = (unsigned short*)(xzr + (size_t)DINNER * M_ROWS * 4); // [4096][1536] bf16
  float*          xdblS = (float*)(ws + alloc((size_t)KSPLIT * M_ROWS * 128 * 4)); // 8 slabs
  unsigned short* xbf   = (unsigned short*)(ws + alloc((size_t)M_ROWS * DMODEL * 2));
  unsigned short* w1bf  = (unsigned short*)(ws + alloc((size_t)2 * DINNER * DMODEL * 2));
  unsigned short* w2bf  = (unsigned short*)(ws + alloc((size_t)128 * DINNER * 2));
  unsigned short* w3bf  = (unsigned short*)(ws + alloc((size_t)DMODEL * DINNER * 2));
  unsigned short* dtlbf = (unsigned short*)(ws + alloc((size_t)M_ROWS * 64 * 2));
  unsigned short* dtwbf = (unsigned short*)(ws + alloc((size_t)DINNER * 64 * 2));
  unsigned short* xcbf  = (unsigned short*)(ws + alloc((size_t)M_ROWS * DINNER * 2));
  unsigned short* xcT   = (unsigned short*)(ws + alloc((size_t)DINNER * M_ROWS * 2));
  unsigned short* szbf  = (unsigned short*)(ws + alloc((size_t)DINNER * M_ROWS * 2));
  float*          BCt   = (float*)(ws + alloc((size_t)B_SZ * 32 * L_SEQ * 4));
  float*          Pbuf  = (float*)(ws + alloc((size_t)NSEG * B_SZ * DINNER * 16 * 4));
  float*          HLbuf = (float*)(ws + alloc((size_t)NSEG * B_SZ * DINNER * 16 * 4));
  float*          HINb  = (float*)(ws + alloc((size_t)NSEG * B_SZ * DINNER * 16 * 4));

  // 1. casts
  cast_all_kernel<<<27264, 256, 0, stream>>>(x, w1, w2, w3, dtw, xbf, w1bf, w2bf, w3bf, dtwbf);
  // 2. xz = x @ W_in^T  (async staging GEMM)
  gemm_async<<<dim3(32, 24), 256, 0, stream>>>(xbf, w1bf, xz, DMODEL, DMODEL, 3072, 0);
  // 3. conv+SiLU -> xcbf/xcT, then z-SiLU -> szT (fused)
  conv_silu_zt<<<dim3(64, 24), 256, 0, stream>>>(xz, cw, cb, xcbf, xcT, szbf);
  // 4. x_dbl slabs = xc @ W_x^T, split-K x8 private slabs
  gemm_async<<<dim3(32, 1, KSPLIT), 256, 0, stream>>>(xcbf, w2bf, xdblS, DINNER,
                                                      DINNER / KSPLIT, 128,
                                                      (long)M_ROWS * 128);
  // 5. slab-reduce + dt_low cast + B/C transpose
  xdbl_pack_kernel<<<1152, 256, 0, stream>>>(xdblS, dtlbf, BCt);
  // 6. dtT = softplus(W_dt @ dt_low^T + b)  [1536][4096], overlays xz
  gemm_dt<<<dim3(12, 32), 256, 0, stream>>>(dtwbf, dtlbf, dtT, 64, M_ROWS, dtb);
  // 7-9. segmented scan (NSEG=8, 4 waves/block, B/C direct-from-L2)
  scan_seg<0><<<dim3(96, 2, NSEG - 1), 256, 0, stream>>>(dtT, xcT, BCt, szbf, alog, Dp,
                                                         nullptr, Pbuf, HLbuf, nullptr);
  scan_comb<<<192, 256, 0, stream>>>(Pbuf, HLbuf, HINb);
  scan_seg<1><<<dim3(96, 2, NSEG), 256, 0, stream>>>(dtT, xcT, BCt, szbf, alog, Dp,
                                                     HINb, nullptr, nullptr, ybf);
  // 10. out = y @ W_out^T
  gemm_async<<<dim3(32, 6), 256, 0, stream>>>(ybf, w3bf, out, DINNER, DINNER, 768, 0);
}

// Round 11
// 271.149 us; speedup vs baseline: 1.2843x; 1.2843x over previous
//
#include <hip/hip_runtime.h>
#include <stdint.h>

#define B_SZ    2
#define L_SEQ   2048
#define DMODEL  768
#define DSTATE  16
#define DINNER  1536
#define DTRANK  48
#define M_ROWS  4096      // B*L
#define NSEG    8
#define SEGL    256
#define NSC     8         // superchunks per segment
#define SCL     32        // steps per superchunk
#define KSPLIT  8         // gemm2 split-K slabs

typedef __attribute__((ext_vector_type(8))) short bf16x8;
typedef __attribute__((ext_vector_type(4))) float f32x4;
typedef __attribute__((ext_vector_type(2))) float f32x2;
typedef __attribute__((ext_vector_type(4))) unsigned int u32x4;
typedef __attribute__((ext_vector_type(2))) unsigned int u32x2;

__device__ __forceinline__ unsigned short f2bf(float f) {
  unsigned int u = __float_as_uint(f);
  u += 0x7FFFu + ((u >> 16) & 1u);          // RNE
  return (unsigned short)(u >> 16);
}
__device__ __forceinline__ unsigned int pack2bf(float a, float b) {
  return (unsigned int)f2bf(a) | ((unsigned int)f2bf(b) << 16);
}
__device__ __forceinline__ float fexp(float x) {
  return __builtin_amdgcn_exp2f(x * 1.44269504088896340736f);
}
__device__ __forceinline__ float sigm(float x) {
  return 1.0f / (1.0f + fexp(-x));
}
// softplus(v) = max(v,0) + ln2*log2(1+exp2(-|v|*log2e)) — 3 HW transcendentals
__device__ __forceinline__ float softplus(float v) {
  float e = __builtin_amdgcn_exp2f(-fabsf(v) * 1.44269504f);
  return fmaxf(v, 0.f) + 0.69314718056f * __builtin_amdgcn_logf(1.f + e);
}

template <int CTRL>
__device__ __forceinline__ float dpp_add(float v) {
  int x = __builtin_amdgcn_update_dpp(0, __float_as_int(v), CTRL, 0xF, 0xF, true);
  return v + __int_as_float(x);
}
__device__ __forceinline__ float quad_sum(float v) {
  v = dpp_add<0xB1>(v);   // quad_perm [1,0,3,2]
  v = dpp_add<0x4E>(v);   // quad_perm [2,3,0,1]
  return v;
}
__device__ __forceinline__ float row16_sum(float v) {
  v = dpp_add<0xB1>(v);
  v = dpp_add<0x4E>(v);
  v = dpp_add<0x124>(v);  // row_ror:4
  v = dpp_add<0x128>(v);  // row_ror:8
  return v;
}

// async global->LDS, 16B per lane; LDS dest is wave-uniform base + lane*16
__device__ __forceinline__ void gload_lds(const unsigned short* g, unsigned short* l) {
  __builtin_amdgcn_global_load_lds((__attribute__((address_space(1))) void*)g,
                                   (__attribute__((address_space(3))) void*)l, 16, 0, 0);
}

// ---------------------------------------------------------------- casts ----
__global__ void cast_all_kernel(const float* __restrict__ x, const float* __restrict__ w1,
                                const float* __restrict__ w2, const float* __restrict__ w3,
                                const float* __restrict__ dtw,
                                unsigned short* __restrict__ xbf, unsigned short* __restrict__ w1bf,
                                unsigned short* __restrict__ w2bf, unsigned short* __restrict__ w3bf,
                                unsigned short* __restrict__ dtwbf) {
  int i = blockIdx.x * 256 + threadIdx.x;
  const int n_x = M_ROWS * DMODEL;
  const int n_w1 = 2 * DINNER * DMODEL;
  const int n_w3 = DMODEL * DINNER;
  const int n_w2 = 128 * DINNER;
  const int n_dtw = DINNER * 64;
  if (i < n_x)  { xbf[i] = f2bf(x[i]); return; }  i -= n_x;
  if (i < n_w1) { w1bf[i] = f2bf(w1[i]); return; } i -= n_w1;
  if (i < n_w3) { w3bf[i] = f2bf(w3[i]); return; } i -= n_w3;
  if (i < n_w2) {
    int row = i / DINNER, col = i - row * DINNER;
    w2bf[i] = (row < (DTRANK + 2 * DSTATE)) ? f2bf(w2[row * DINNER + col]) : (unsigned short)0;
    return;
  }
  i -= n_w2;
  if (i < n_dtw) {
    int row = i >> 6, col = i & 63;
    dtwbf[i] = (col < DTRANK) ? f2bf(dtw[row * DTRANK + col]) : (unsigned short)0;
  }
}

// merged: reduce 8 gemm2 slabs + cast dt_low (padded K=64) + B/C repack.
// BCt layout: [b][l8 = l/8][row 0..31][j = l%8], row = s for B, 16+s for C.
// A wave's per-8-step B read is then lane(s): 8 consecutive floats at s*32B
// -> one contiguous 512B segment (fully coalesced; dl-lanes broadcast).
__global__ void xdbl_pack_kernel(const float* __restrict__ xdblS,
                                 unsigned short* __restrict__ dtlbf,
                                 float* __restrict__ BCt) {
  const int SLAB = M_ROWS * 128;
  int i = blockIdx.x * 256 + threadIdx.x;
  const int n_dtl = M_ROWS * 64;            // 262144
  if (i < n_dtl) {
    int row = i >> 6, col = i & 63;
    if (col < DTRANK) {
      float v = 0.f;
#pragma unroll
      for (int z = 0; z < KSPLIT; z++) v += xdblS[(size_t)z * SLAB + row * 128 + col];
      dtlbf[i] = f2bf(v);
    } else dtlbf[i] = 0;
    return;
  }
  i -= n_dtl;                               // 32768 entries
  int l4 = i & 511;                         // group of 4 steps
  int k  = (i >> 9) & 31;                   // row (B: 0-15, C: 16-31)
  int b  = (i >> 14) & 1;
  f32x4 o;
#pragma unroll
  for (int j = 0; j < 4; j++) {
    float v = 0.f;
    size_t base = ((size_t)b * L_SEQ + l4 * 4 + j) * 128 + DTRANK + k;
#pragma unroll
    for (int z = 0; z < KSPLIT; z++) v += xdblS[(size_t)z * SLAB + base];
    o[j] = v;
  }
  // steps l4*4..l4*4+3 live in l8 = l4>>1, j-offset (l4&1)*4
  size_t dst = (((size_t)b * (L_SEQ / 8) + (l4 >> 1)) * 32 + k) * 8 + (l4 & 1) * 4;
  *(f32x4*)(BCt + dst) = o;
}

// ------------------------------- async bf16 MFMA GEMM (B^T), m97 structure ----
__global__ __launch_bounds__(256, 2) void gemm_async(
    const unsigned short* __restrict__ A, const unsigned short* __restrict__ Bt,
    float* __restrict__ C, int K, int KS, int ldc, long slab) {
  __shared__ unsigned short As[128 * 32];
  __shared__ unsigned short Bs[128 * 32];
  const int tid = threadIdx.x;
  const int lane = tid & 63;
  const int wv = tid >> 6;
  const int m0 = blockIdx.x * 128;
  const int n0 = blockIdx.y * 128;
  const int ks = blockIdx.z * KS, ke = ks + KS;
  float* Cz = C + (size_t)blockIdx.z * slab;
  const int wr = (wv >> 1) * 64, wc = (wv & 1) * 64;
  const int lm = lane & 15, q = lane >> 4;
  const int srow = wv * 16 + (lane >> 2);   // staging row within 64-row half
  const int scol = (lane & 3) * 8;          // staging col (elems)

  f32x4 acc[4][4] = {};

  for (int k0 = ks; k0 < ke; k0 += 32) {
#pragma unroll
    for (int j = 0; j < 2; j++) {
      gload_lds(A + (size_t)(m0 + j * 64 + srow) * K + k0 + scol, &As[(j * 64 + wv * 16) * 32]);
      gload_lds(Bt + (size_t)(n0 + j * 64 + srow) * K + k0 + scol, &Bs[(j * 64 + wv * 16) * 32]);
    }
    __syncthreads();
    bf16x8 af[4], bq[4];
#pragma unroll
    for (int mt = 0; mt < 4; mt++)
      af[mt] = *(const bf16x8*)&As[(wr + mt * 16 + lm) * 32 + q * 8];
#pragma unroll
    for (int nt = 0; nt < 4; nt++)
      bq[nt] = *(const bf16x8*)&Bs[(wc + nt * 16 + lm) * 32 + q * 8];
#pragma unroll
    for (int mt = 0; mt < 4; mt++)
#pragma unroll
      for (int nt = 0; nt < 4; nt++)
        acc[mt][nt] = __builtin_amdgcn_mfma_f32_16x16x32_bf16(af[mt], bq[nt], acc[mt][nt], 0, 0, 0);
    __syncthreads();
  }

#pragma unroll
  for (int mt = 0; mt < 4; mt++) {
    int row0 = m0 + wr + mt * 16 + q * 4;
#pragma unroll
    for (int nt = 0; nt < 4; nt++) {
      int col = n0 + wc + nt * 16 + lm;
#pragma unroll
      for (int i = 0; i < 4; i++)
        Cz[(size_t)(row0 + i) * ldc + col] = acc[mt][nt][i];
    }
  }
}

// --------------------- padded VGPR-staging GEMM for the dt projection ----
__global__ __launch_bounds__(256, 2) void gemm_dt(
    const unsigned short* __restrict__ A, const unsigned short* __restrict__ Bt,
    float* __restrict__ C, int K, int ldc, const float* __restrict__ bias) {
  __shared__ unsigned short As[128 * 40];
  __shared__ unsigned short Bs[128 * 40];
  const int tid = threadIdx.x;
  const int m0 = blockIdx.x * 128;
  const int n0 = blockIdx.y * 128;
  const int lane = tid & 63;
  const int wave = tid >> 6;
  const int wr = (wave >> 1) * 64, wc = (wave & 1) * 64;
  const int lm = lane & 15, q = lane >> 4;
  const int r = tid >> 2, sg = (tid & 3) * 8;

  f32x4 acc[4][4] = {};

  for (int k0 = 0; k0 < K; k0 += 32) {
    u32x4 a0 = *(const u32x4*)(A + (size_t)(m0 + r) * K + k0 + sg);
    u32x4 a1 = *(const u32x4*)(A + (size_t)(m0 + r + 64) * K + k0 + sg);
    u32x4 b0 = *(const u32x4*)(Bt + (size_t)(n0 + r) * K + k0 + sg);
    u32x4 b1 = *(const u32x4*)(Bt + (size_t)(n0 + r + 64) * K + k0 + sg);
    __syncthreads();
    *(u32x4*)&As[r * 40 + sg] = a0;
    *(u32x4*)&As[(r + 64) * 40 + sg] = a1;
    *(u32x4*)&Bs[r * 40 + sg] = b0;
    *(u32x4*)&Bs[(r + 64) * 40 + sg] = b1;
    __syncthreads();
    bf16x8 af[4], bq[4];
#pragma unroll
    for (int mt = 0; mt < 4; mt++)
      af[mt] = *(const bf16x8*)&As[(wr + mt * 16 + lm) * 40 + q * 8];
#pragma unroll
    for (int nt = 0; nt < 4; nt++)
      bq[nt] = *(const bf16x8*)&Bs[(wc + nt * 16 + lm) * 40 + q * 8];
#pragma unroll
    for (int mt = 0; mt < 4; mt++)
#pragma unroll
      for (int nt = 0; nt < 4; nt++)
        acc[mt][nt] = __builtin_amdgcn_mfma_f32_16x16x32_bf16(af[mt], bq[nt], acc[mt][nt], 0, 0, 0);
  }

#pragma unroll
  for (int mt = 0; mt < 4; mt++) {
    int row0 = m0 + wr + mt * 16 + q * 4;
    float bs4[4];
#pragma unroll
    for (int i = 0; i < 4; i++) bs4[i] = bias[row0 + i];
#pragma unroll
    for (int nt = 0; nt < 4; nt++) {
      int col = n0 + wc + nt * 16 + lm;
#pragma unroll
      for (int i = 0; i < 4; i++)
        C[(size_t)(row0 + i) * ldc + col] = softplus(acc[mt][nt][i] + bs4[i]);
    }
  }
}

// ---- fused depthwise conv+SiLU -> xcbf + xcT, then z-half SiLU -> szT ------
__global__ __launch_bounds__(256) void conv_silu_zt(const float* __restrict__ xz,
                                                    const float* __restrict__ cw,
                                                    const float* __restrict__ cb,
                                                    unsigned short* __restrict__ xcbf,
                                                    unsigned short* __restrict__ xcT,
                                                    unsigned short* __restrict__ szT) {
  __shared__ float tl[67 * 68];
  __shared__ unsigned short xs[64 * 80];
  __shared__ float cws[256];
  __shared__ float cbs[64];
  const int r0 = blockIdx.x * 64;     // global row b*L+l
  const int c0 = blockIdx.y * 64;     // channel d
  const int t = threadIdx.x;
  cws[t] = cw[(c0 + (t >> 2)) * 4 + (t & 3)];
  if (t < 64) cbs[t] = cb[c0 + t];
  const bool lowedge = (r0 & (L_SEQ - 1)) == 0;
#pragma unroll
  for (int it = 0; it < 5; it++) {
    int idx = t + it * 256;
    int rr = idx >> 4;
    int cs4 = (idx & 15) * 4;
    if (rr < 67) {
      f32x4 v;
      if (lowedge && rr < 3) v = (f32x4){0.f, 0.f, 0.f, 0.f};
      else v = *(const f32x4*)(xz + (size_t)(r0 + rr - 3) * 3072 + c0 + cs4);
      *(f32x4*)&tl[rr * 68 + cs4] = v;
    }
  }
  __syncthreads();
  {
    const int cs = (t & 15) * 4;
    f32x4 w0, w1, w2, w3, cbv;
#pragma unroll
    for (int j = 0; j < 4; j++) {
      w0[j] = cws[(cs + j) * 4 + 0];
      w1[j] = cws[(cs + j) * 4 + 1];
      w2[j] = cws[(cs + j) * 4 + 2];
      w3[j] = cws[(cs + j) * 4 + 3];
      cbv[j] = cbs[cs + j];
    }
#pragma unroll
    for (int it = 0; it < 4; it++) {
      int r = (t >> 4) + it * 16;
      f32x4 t0 = *(const f32x4*)&tl[(r + 0) * 68 + cs];
      f32x4 t1 = *(const f32x4*)&tl[(r + 1) * 68 + cs];
      f32x4 t2 = *(const f32x4*)&tl[(r + 2) * 68 + cs];
      f32x4 t3 = *(const f32x4*)&tl[(r + 3) * 68 + cs];
      f32x4 acc = cbv + w0 * t0 + w1 * t1 + w2 * t2 + w3 * t3;
#pragma unroll
      for (int j = 0; j < 4; j++) acc[j] = acc[j] * sigm(acc[j]);
      u32x2 pk;
      pk[0] = pack2bf(acc[0], acc[1]);
      pk[1] = pack2bf(acc[2], acc[3]);
      *(u32x2*)(xcbf + (size_t)(r0 + r) * DINNER + c0 + cs) = pk;
      *(u32x2*)&xs[r * 80 + cs] = pk;
    }
  }
  __syncthreads();
#pragma unroll
  for (int it = 0; it < 4; it++) {
    int idx = t + it * 256;
    int rr = idx >> 4, cs = idx & 15;
    f32x4 v = *(const f32x4*)(xz + (size_t)(r0 + rr) * 3072 + DINNER + c0 + cs * 4);
#pragma unroll
    for (int p = 0; p < 4; p++) v[p] = v[p] * sigm(v[p]);
    *(f32x4*)&tl[rr * 68 + cs * 4] = v;
  }
#pragma unroll
  for (int it = 0; it < 2; it++) {
    int idx = t + it * 256;
    int cc = idx & 63, rs = idx >> 6;
    unsigned int w[4];
#pragma unroll
    for (int p = 0; p < 4; p++) {
      unsigned int lo = xs[(rs * 8 + 2 * p) * 80 + cc];
      unsigned int hi = xs[(rs * 8 + 2 * p + 1) * 80 + cc];
      w[p] = lo | (hi << 16);
    }
    *(u32x4*)(xcT + (size_t)(c0 + cc) * M_ROWS + r0 + rs * 8) = *(u32x4*)w;
  }
  __syncthreads();
#pragma unroll
  for (int it = 0; it < 2; it++) {
    int idx = t + it * 256;
    int cc = idx & 63, rs = idx >> 6;
    unsigned int w[4];
#pragma unroll
    for (int p = 0; p < 4; p++)
      w[p] = pack2bf(tl[(rs * 8 + 2 * p) * 68 + cc], tl[(rs * 8 + 2 * p + 1) * 68 + cc]);
    *(u32x4*)(szT + (size_t)(c0 + cc) * M_ROWS + r0 + rs * 8) = *(u32x4*)w;
  }
}

// ------------------------------------------------ segmented selective scan ----
// 256-thr block = 4 waves, each wave an independent (4-channel group, batch,
// segment) scanner. dt/xc/sz staged via small wave-private LDS; B/C read
// directly from global in the step-blocked layout (coalesced 512B segments,
// dl-broadcast). No barriers. LDS: FULL=1 ~16 KB, FULL=0 ~4.6 KB.
template <int FULL>
__global__ __launch_bounds__(256) void scan_seg(
    const float* __restrict__ dtT, const unsigned short* __restrict__ xcT,
    const float* __restrict__ BCt, const unsigned short* __restrict__ szT,
    const float* __restrict__ A_log, const float* __restrict__ Dp,
    const float* __restrict__ HIN, float* __restrict__ P, float* __restrict__ HL,
    unsigned short* __restrict__ ybf) {
  __shared__ float dtS[4][4 * 36];
  __shared__ float dtxS[4][4 * 36];
  __shared__ unsigned int xcR[FULL ? 4 : 1][FULL ? 4 * 18 : 1];
  __shared__ unsigned int szR[FULL ? 4 : 1][FULL ? 4 * 18 : 1];
  __shared__ float ysh[FULL ? 4 : 1][FULL ? 16 * 36 : 1];
  const int tid = threadIdx.x;
  const int wv = tid >> 6;
  const int lane = tid & 63;
  const int s = lane & 15, dl = lane >> 4;
  const int d0 = blockIdx.x * 16 + wv * 4;
  const int d = d0 + dl;
  const int b = blockIdx.y;
  const int seg = blockIdx.z;
  const int lseg = seg * SEGL;
  const size_t rbase = (size_t)b * L_SEQ + lseg;
  const float a2 = -fexp(A_log[d * 16 + s]) * 1.44269504f;
  const float dpv = Dp[d];
  const float* dtbase = dtT + (size_t)d0 * M_ROWS + rbase;
  const unsigned short* xcbase = xcT + (size_t)d0 * M_ROWS + rbase;
  const unsigned short* szbase = szT + (size_t)d0 * M_ROWS + rbase;
  // step-blocked B/C: row s at BCb + (l8*32 + s)*8, C at +128 floats
  const float* BCb = BCt + ((size_t)b * (L_SEQ / 8) + seg * 32) * 32 * 8 + s * 8;
  const int ch = lane >> 4, li = lane & 15;     // staging map
  float* dtSw = dtS[wv];
  float* dtxSw = dtxS[wv];
  float* ywp = FULL ? &ysh[wv][(dl * 4 + (s >> 2)) * 36 + (s & 3)] : nullptr;
  const bool sb0 = (s & 1) != 0, sb1 = (s & 2) != 0;
  float h = 0.f, sdt = 0.f;
  size_t o = (((size_t)seg * B_SZ + b) * DINNER + d) * 16 + s;
  if (FULL) h = HIN[o];

#pragma unroll 1
  for (int c = 0; c < NSC; c++) {
    const int l0 = c * SCL;
    {
      f32x2 dt = *(const f32x2*)(dtbase + (size_t)ch * M_ROWS + l0 + li * 2);
      unsigned int xc = *(const unsigned int*)(xcbase + (size_t)ch * M_ROWS + l0 + li * 2);
      if (!FULL) sdt += dt[0] + dt[1];
      f32x2 xf;
      xf[0] = __uint_as_float(xc << 16);
      xf[1] = __uint_as_float(xc & 0xFFFF0000u);
      *(f32x2*)&dtSw[ch * 36 + li * 2] = dt;
      f32x2 dtx = dt * xf;
      *(f32x2*)&dtxSw[ch * 36 + li * 2] = dtx;
      if (FULL) {
        xcR[wv][ch * 18 + li] = xc;
        szR[wv][ch * 18 + li] = *(const unsigned int*)(szbase + (size_t)ch * M_ROWS + l0 + li * 2);
      }
    }
#pragma unroll
    for (int g = 0; g < 4; g++) {
      const int l0g = g * 8;
      const float* Bp = BCb + (size_t)(c * 4 + g) * 256;   // l8 block stride = 32*8 floats
      f32x4 dta = *(const f32x4*)&dtSw[dl * 36 + l0g];
      f32x4 dtb = *(const f32x4*)&dtSw[dl * 36 + l0g + 4];
      f32x4 xa  = *(const f32x4*)&dtxSw[dl * 36 + l0g];
      f32x4 xb  = *(const f32x4*)&dtxSw[dl * 36 + l0g + 4];
      f32x4 Ba  = *(const f32x4*)(Bp);
      f32x4 Bb  = *(const f32x4*)(Bp + 4);
      f32x4 Ca, Cb;
      if (FULL) {
        Ca = *(const f32x4*)(Bp + 128);
        Cb = *(const f32x4*)(Bp + 132);
      }
      float p8[8];
#pragma unroll
      for (int j = 0; j < 8; j++) {
        float dtj = (j < 4) ? dta[j] : dtb[j - 4];
        float dxj = (j < 4) ? xa[j]  : xb[j - 4];
        float Bj  = (j < 4) ? Ba[j]  : Bb[j - 4];
        float a = __builtin_amdgcn_exp2f(dtj * a2);
        h = a * h + dxj * Bj;
        if (FULL) {
          float Cj = (j < 4) ? Ca[j] : Cb[j - 4];
          p8[j] = h * Cj;
        }
      }
      if (FULL) {
#pragma unroll
        for (int half = 0; half < 2; half++) {
          float q0 = quad_sum(p8[half * 4 + 0]);
          float q1 = quad_sum(p8[half * 4 + 1]);
          float q2 = quad_sum(p8[half * 4 + 2]);
          float q3 = quad_sum(p8[half * 4 + 3]);
          float v01 = sb0 ? q1 : q0;
          float v23 = sb0 ? q3 : q2;
          ywp[g * 8 + half * 4] = sb1 ? v23 : v01;
        }
      }
    }
    if (FULL) {
      f32x2 y0 = *(const f32x2*)&ysh[wv][(dl * 4 + 0) * 36 + s * 2];
      f32x2 y1 = *(const f32x2*)&ysh[wv][(dl * 4 + 1) * 36 + s * 2];
      f32x2 y2 = *(const f32x2*)&ysh[wv][(dl * 4 + 2) * 36 + s * 2];
      f32x2 y3 = *(const f32x2*)&ysh[wv][(dl * 4 + 3) * 36 + s * 2];
      f32x2 ys = y0 + y1 + y2 + y3;
      unsigned int xcu = xcR[wv][dl * 18 + s];
      unsigned int szu = szR[wv][dl * 18 + s];
      float xcf[2] = {__uint_as_float(xcu << 16), __uint_as_float(xcu & 0xFFFF0000u)};
      float szf[2] = {__uint_as_float(szu << 16), __uint_as_float(szu & 0xFFFF0000u)};
      size_t rr0 = rbase + c * SCL + s * 2;
#pragma unroll
      for (int i = 0; i < 2; i++) {
        float yv = ys[i] + xcf[i] * dpv;
        ybf[(rr0 + i) * DINNER + d] = f2bf(yv * szf[i]);
      }
    }
  }
  if (!FULL) {
    sdt = row16_sum(sdt);
    P[o] = __builtin_amdgcn_exp2f(a2 * sdt);
    HL[o] = h;
  }
}

__global__ void scan_comb(const float* __restrict__ P, const float* __restrict__ HL,
                          float* __restrict__ HIN) {
  int tg = blockIdx.x * 256 + threadIdx.x;  // 49152
  int s = tg & 15;
  int rem = tg >> 4;
  int d = rem % DINNER;
  int b = rem / DINNER;
  float h = 0.f;
  for (int g = 0; g < NSEG; g++) {
    size_t o = (((size_t)g * B_SZ + b) * DINNER + d) * 16 + s;
    HIN[o] = h;
    if (g < NSEG - 1) h = P[o] * h + HL[o];
  }
}

// -------------------------------------------------------------- launcher ----
extern "C" void kernel_launch(void* const* d_in, const int* in_sizes, int n_in,
                              void* d_out, int out_size, void* d_ws, size_t ws_size,
                              hipStream_t stream) {
  const float* x    = (const float*)d_in[0];
  const float* w1   = (const float*)d_in[1];
  const float* cw   = (const float*)d_in[2];
  const float* cb   = (const float*)d_in[3];
  const float* alog = (const float*)d_in[4];
  const float* Dp   = (const float*)d_in[5];
  const float* w2   = (const float*)d_in[6];
  const float* dtw  = (const float*)d_in[7];
  const float* dtb  = (const float*)d_in[8];
  const float* w3   = (const float*)d_in[9];
  float* out = (float*)d_out;
  char* ws = (char*)d_ws;

  size_t off = 0;
  auto alloc = [&](size_t bytes) { size_t o = off; off += (bytes + 255) & ~(size_t)255; return o; };
  // xz region reused: after conv+szT consume it, dtT and ybf overlay it.
  char*           xzr   = ws + alloc((size_t)M_ROWS * 3072 * 4);
  float*          xz    = (float*)xzr;
  float*          dtT   = (float*)xzr;                                          // [1536][4096] f32
  unsigned short* ybf   = (unsigned short*)(xzr + (size_t)DINNER * M_ROWS * 4); // [4096][1536] bf16
  float*          xdblS = (float*)(ws + alloc((size_t)KSPLIT * M_ROWS * 128 * 4)); // 8 slabs
  unsigned short* xbf   = (unsigned short*)(ws + alloc((size_t)M_ROWS * DMODEL * 2));
  unsigned short* w1bf  = (unsigned short*)(ws + alloc((size_t)2 * DINNER * DMODEL * 2));
  unsigned short* w2bf  = (unsigned short*)(ws + alloc((size_t)128 * DINNER * 2));
  unsigned short* w3bf  = (unsigned short*)(ws + alloc((size_t)DMODEL * DINNER * 2));
  unsigned short* dtlbf = (unsigned short*)(ws + alloc((size_t)M_ROWS * 64 * 2));
  unsigned short* dtwbf = (unsigned short*)(ws + alloc((size_t)DINNER * 64 * 2));
  unsigned short* xcbf  = (unsigned short*)(ws + alloc((size_t)M_ROWS * DINNER * 2));
  unsigned short* xcT   = (unsigned short*)(ws + alloc((size_t)DINNER * M_ROWS * 2));
  unsigned short* szbf  = (unsigned short*)(ws + alloc((size_t)DINNER * M_ROWS * 2));
  float*          BCt   = (float*)(ws + alloc((size_t)B_SZ * 32 * L_SEQ * 4));
  float*          Pbuf  = (float*)(ws + alloc((size_t)NSEG * B_SZ * DINNER * 16 * 4));
  float*          HLbuf = (float*)(ws + alloc((size_t)NSEG * B_SZ * DINNER * 16 * 4));
  float*          HINb  = (float*)(ws + alloc((size_t)NSEG * B_SZ * DINNER * 16 * 4));

  // 1. casts
  cast_all_kernel<<<27264, 256, 0, stream>>>(x, w1, w2, w3, dtw, xbf, w1bf, w2bf, w3bf, dtwbf);
  // 2. xz = x @ W_in^T  (async staging GEMM)
  gemm_async<<<dim3(32, 24), 256, 0, stream>>>(xbf, w1bf, xz, DMODEL, DMODEL, 3072, 0);
  // 3. conv+SiLU -> xcbf/xcT, then z-SiLU -> szT (fused)
  conv_silu_zt<<<dim3(64, 24), 256, 0, stream>>>(xz, cw, cb, xcbf, xcT, szbf);
  // 4. x_dbl slabs = xc @ W_x^T, split-K x8 private slabs
  gemm_async<<<dim3(32, 1, KSPLIT), 256, 0, stream>>>(xcbf, w2bf, xdblS, DINNER,
                                                      DINNER / KSPLIT, 128,
                                                      (long)M_ROWS * 128);
  // 5. slab-reduce + dt_low cast + B/C repack (step-blocked layout)
  xdbl_pack_kernel<<<1152, 256, 0, stream>>>(xdblS, dtlbf, BCt);
  // 6. dtT = softplus(W_dt @ dt_low^T + b)  [1536][4096], overlays xz
  gemm_dt<<<dim3(12, 32), 256, 0, stream>>>(dtwbf, dtlbf, dtT, 64, M_ROWS, dtb);
  // 7-9. segmented scan (NSEG=8, 4 waves/block, coalesced direct B/C)
  scan_seg<0><<<dim3(96, 2, NSEG - 1), 256, 0, stream>>>(dtT, xcT, BCt, szbf, alog, Dp,
                                                         nullptr, Pbuf, HLbuf, nullptr);
  scan_comb<<<192, 256, 0, stream>>>(Pbuf, HLbuf, HINb);
  scan_seg<1><<<dim3(96, 2, NSEG), 256, 0, stream>>>(dtT, xcT, BCt, szbf, alog, Dp,
                                                     HINb, nullptr, nullptr, ybf);
  // 10. out = y @ W_out^T
  gemm_async<<<dim3(32, 6), 256, 0, stream>>>(ybf, w3bf, out, DINNER, DINNER, 768, 0);
}